// Round 13
// baseline (318.746 us; speedup 1.0000x reference)
//
#include <hip/hip_runtime.h>
#include <hip/hip_bf16.h>

#define B_  8
#define D_  128
#define K_  7
#define Q_  256
#define G0_ 511
#define G0P 512
#define G1_ 512
#define F1_ 512
#define F2_ 1024
#define OUT_ 16

typedef __bf16 bf16x8 __attribute__((ext_vector_type(8)));
typedef float  f32x4  __attribute__((ext_vector_type(4)));

// async global->LDS: one instruction = 64 lanes x 16B = 1KB.
// LDS dest = wave-uniform base + lane*16B.
#define GL2LDS(g, l) __builtin_amdgcn_global_load_lds(                        \
    (const __attribute__((address_space(1))) void*)(g),                       \
    (__attribute__((address_space(3))) void*)(l), 16, 0, 0)

// ---------------------------------------------------------------------------
// k_prep: fused preprocessing, 2092 blocks x 256 threads (R8/R10-measured).
// R16: also zeroes the k_f23 last-block counter each iteration.
__global__ void k_prep(const float* __restrict__ x, const float* __restrict__ g0w,
                       const float* __restrict__ g0b, const float* __restrict__ qst,
                       const float* __restrict__ g1w, const float* __restrict__ g1b,
                       const float* __restrict__ f1w, const float* __restrict__ f2w,
                       const float* __restrict__ f3w,
                       float* __restrict__ u, float* __restrict__ v,
                       __bf16* __restrict__ w1t, float* __restrict__ qterm,
                       float* __restrict__ xg, float* __restrict__ f1t,
                       float* __restrict__ f2t, float* __restrict__ f3t,
                       unsigned* __restrict__ cnt) {
    const int blk = blockIdx.x;
    const int t   = threadIdx.x;
    if (blk < 1024) {
        __shared__ float xs[8];
        if (t < K_) xs[t] = x[blk * K_ + t];
        __syncthreads();
        #pragma unroll
        for (int h = 0; h < 2; ++h) {
            const int g = t + h * 256;
            float su = 0.f, sv = 0.f;
            if (g < G0_) {
                #pragma unroll
                for (int k = 0; k < K_; ++k) {
                    su += xs[k] * g0w[k * G0_ + g];
                    sv += xs[k] * g0w[(K_ + k) * G0_ + g];
                }
                su += g0b[g];
            }
            u[blk * G0P + g] = (g < G0_) ? su : 0.f;
            v[blk * G0P + g] = (g < G0_) ? sv : 0.f;
        }
    } else if (blk < 1280) {
        // R3-verified: w1t[kq*16384 + n*32 + slot*8 + j], slot = chunk^((n>>1)&3)
        __shared__ __bf16 tile[32][33];
        const int bb = blk - 1024;
        const int bx = bb & 15, by = bb >> 4;   // by = kq tile (k = by*32+c)
        const int r = t >> 5, c = t & 31;
        #pragma unroll
        for (int i = 0; i < 4; ++i) {
            const int k = by * 32 + r + i * 8;
            const int n = bx * 32 + c;
            tile[r + i * 8][c] = (__bf16)((k < G0_) ? g1w[k * G1_ + n] : 0.f);
        }
        __syncthreads();
        #pragma unroll
        for (int i = 0; i < 4; ++i) {
            const int n = bx * 32 + r + i * 8;
            const int cc = (c >> 3) & 3, j = c & 7;
            const int slot = cc ^ ((n >> 1) & 3);
            w1t[by * 16384 + n * 32 + slot * 8 + j] = tile[c][r + i * 8];
        }
    } else if (blk < 1312) {
        __shared__ float qs[256];
        __shared__ float red[2][128];
        const int qb = blk - 1280;
        const int b = qb >> 2, nb = (qb & 3) << 7;
        qs[t] = qst[b * Q_ + t];
        __syncthreads();
        const int n = nb + (t & 127);
        const int qh = (t >> 7) * 128;
        float s = 0.f;
        #pragma unroll 8
        for (int q = 0; q < 128; ++q)
            s += qs[qh + q] * g1w[(G0_ + qh + q) * G1_ + n];
        red[t >> 7][t & 127] = s;
        __syncthreads();
        if (t < 128)
            qterm[b * G1_ + nb + t] = red[0][t] + red[1][t] + g1b[nb + t];
    } else if (blk < 1320) {
        const int b = blk - 1312;
        xg[b * G1_ + t] = 0.f;
        xg[b * G1_ + 256 + t] = 0.f;
        if (blk == 1312 && t == 0) cnt[0] = 0u;
    } else if (blk < 1576) {
        __shared__ float tile[32][33];
        const int j = blk - 1320;
        const int bo = j & 15, bk = j >> 4;
        const int r = t >> 5, c = t & 31;
        #pragma unroll
        for (int i = 0; i < 4; ++i)
            tile[r + i * 8][c] = f1w[(bk * 32 + r + i * 8) * F1_ + bo * 32 + c];
        __syncthreads();
        #pragma unroll
        for (int i = 0; i < 4; ++i)
            f1t[(bo * 32 + r + i * 8) * G1_ + bk * 32 + c] = tile[c][r + i * 8];
    } else if (blk < 2088) {
        __shared__ float tile[32][33];
        const int j = blk - 1576;
        const int bo = j & 31, bk = j >> 5;
        const int r = t >> 5, c = t & 31;
        #pragma unroll
        for (int i = 0; i < 4; ++i)
            tile[r + i * 8][c] = f2w[(bk * 32 + r + i * 8) * F2_ + bo * 32 + c];
        __syncthreads();
        #pragma unroll
        for (int i = 0; i < 4; ++i)
            f2t[(bo * 32 + r + i * 8) * F1_ + bk * 32 + c] = tile[c][r + i * 8];
    } else {
        const int k = (blk - 2088) * 256 + t;
        float4 r0 = *(const float4*)(f3w + k * OUT_);
        float4 r1 = *(const float4*)(f3w + k * OUT_ + 4);
        float4 r2 = *(const float4*)(f3w + k * OUT_ + 8);
        float4 r3 = *(const float4*)(f3w + k * OUT_ + 12);
        const float rr[16] = {r0.x,r0.y,r0.z,r0.w, r1.x,r1.y,r1.z,r1.w,
                              r2.x,r2.y,r2.z,r2.w, r3.x,r3.y,r3.z,r3.w};
        #pragma unroll
        for (int o = 0; o < 16; ++o) f3t[o * F2_ + k] = rr[o];
    }
}

// ---------------------------------------------------------------------------
// k_pair R16 = R10/R15's measured-best core, UNCHANGED: 512 thr, 64x64/wave,
// acc[4][4], __launch_bounds__(512,4) (R12 proved 6 waves spills),
// counted-vmcnt 3-deep Bt, conflict-free XOR-swizzled At, T5 setprio.
__global__ __launch_bounds__(512, 4)
void k_pair(const float* __restrict__ u, const float* __restrict__ v,
            const __bf16* __restrict__ w1t, const float* __restrict__ qterm,
            float* __restrict__ xg) {
    __shared__ float  v_a[512];
    __shared__ __bf16 At[2][4096];     // [buf][mtile(8)][lane(64)*8]  16 KB
    __shared__ __bf16 Bt[3][8192];     // [buf][n_local(256)][32k swz] 48 KB
    __shared__ float  ebuf[8][64];

    const int bid  = blockIdx.x;
    const int b    = bid >> 8;
    const int a    = (bid >> 1) & 127;
    const int nbase = (bid & 1) << 8;
    const int tid  = threadIdx.x;
    const int wave = tid >> 6, lane = tid & 63;
    const int quad = lane >> 4, l15 = lane & 15;
    const int wm   = wave >> 2;            // m-half: rows [wm*64, +64)
    const int wn   = wave & 3;             // n-quarter: cols [wn*64, +64)
    const int nloc = wn * 64;
    const int mtg  = wm * 4;               // wave's mtile base (4 mtiles)
    const int swz  = (l15 >> 1) & 3;

    // B staging: wave issues 2 DMA instrs, instr j covers n_local [wave*32+j*16,+16)
    const int iw0 = wave * 2;
    const __bf16* gsrc = w1t + (size_t)(nbase + iw0 * 16 + (lane >> 2)) * 32
                             + (lane & 3) * 8;

    // A staging geometry: thread -> (m = tid>>2, k-off = (tid&3)*8), XOR-swizzled
    const int sm = tid >> 2;
    const int q8 = tid & 3;
    const float* urow = u + (size_t)(b * D_ + sm) * G0P + q8 * 8;
    const int woff = ((sm >> 4) * 512 + q8 * 128 + (sm & 15) * 8)
                   ^ (((q8 << 1) | ((sm >> 3) & 1)) << 3);
    // swizzled read lane offset: elem lane*8 with byte-bits[7:9] XORed into [4:6]
    const int afoff = (lane ^ (lane >> 3)) * 8;

    f32x4 acc[4][4];
    #pragma unroll
    for (int mt = 0; mt < 4; ++mt)
        #pragma unroll
        for (int nt = 0; nt < 4; ++nt)
            acc[mt][nt] = (f32x4){0.f, 0.f, 0.f, 0.f};

    float4 ua, ub;
    auto load_u = [&](int kq) {
        const float* p = urow + kq * 32;
        ua = *(const float4*)p;
        ub = *(const float4*)(p + 4);
    };
    auto stage_B = [&](int buf, int kq) {
        const __bf16* g = gsrc + (size_t)kq * 16384;
        __bf16* l = &Bt[buf][iw0 * 512];
        GL2LDS(g, l);
        GL2LDS(g + 512, l + 512);
    };
    auto write_A = [&](int buf, int kq) {
        const float* vp = v_a + kq * 32 + q8 * 8;
        const float4 va = *(const float4*)vp;
        const float4 vb = *(const float4*)(vp + 4);
        bf16x8 h;
        h[0] = (__bf16)fmaxf(ua.x + va.x, 0.f);
        h[1] = (__bf16)fmaxf(ua.y + va.y, 0.f);
        h[2] = (__bf16)fmaxf(ua.z + va.z, 0.f);
        h[3] = (__bf16)fmaxf(ua.w + va.w, 0.f);
        h[4] = (__bf16)fmaxf(ub.x + vb.x, 0.f);
        h[5] = (__bf16)fmaxf(ub.y + vb.y, 0.f);
        h[6] = (__bf16)fmaxf(ub.z + vb.z, 0.f);
        h[7] = (__bf16)fmaxf(ub.w + vb.w, 0.f);
        *(bf16x8*)&At[buf][woff] = h;
    };

    // ---- prologue (R4 invariants, counts adjusted to 2 u + 2 DMA) ----
    // vmcnt FIFO: v-row, u(0) x2, || fence ||, DMA buf0 x2, DMA buf1 x2.
    float4 vq;
    if (tid < 128) vq = *(const float4*)(v + (b * D_ + a) * G0P + tid * 4);
    load_u(0);
    asm volatile("" ::: "memory");       // pin: v/u loads issue before DMAs
    stage_B(0, 0);
    stage_B(1, 1);
    if (tid < 128) *(float4*)(v_a + tid * 4) = vq;   // waits v (counted)
    asm volatile("s_waitcnt lgkmcnt(0)\n\ts_barrier" ::: "memory");  // v_a visible
    write_A(0, 0);                        // u-consume: vmcnt(4), DMAs stay out
    // drain own buf0 DMAs (2 oldest), keep buf1's 2 in flight; publish At[0]
    asm volatile("s_waitcnt vmcnt(2) lgkmcnt(0)\n\ts_barrier" ::: "memory");

    int bcur = 0, bnxt = 1, bstg = 2;
    for (int kq = 0; kq < 16; ++kq) {
        const int abuf = kq & 1;
        if (kq < 15) load_u(kq + 1);          // issue u first (older than DMA)
        asm volatile("" ::: "memory");        // pin u before DMA in vmcnt FIFO
        if (kq < 14) stage_B(bstg, kq + 2);   // async DMA, 2 iterations ahead

        bf16x8 af[4];
        const __bf16* atb = &At[abuf][mtg * 512 + afoff];
        #pragma unroll
        for (int mt = 0; mt < 4; ++mt)
            af[mt] = *(const bf16x8*)(atb + mt * 512);
        bf16x8 bfr[4];
        const __bf16* btb = &Bt[bcur][(nloc + l15) * 32 + ((quad ^ swz) << 3)];
        #pragma unroll
        for (int nt = 0; nt < 4; ++nt)
            bfr[nt] = *(const bf16x8*)(btb + nt * 512);
        __builtin_amdgcn_s_setprio(1);
        #pragma unroll
        for (int mt = 0; mt < 4; ++mt)
            #pragma unroll
            for (int nt = 0; nt < 4; ++nt)
                acc[mt][nt] = __builtin_amdgcn_mfma_f32_16x16x32_bf16(
                    af[mt], bfr[nt], acc[mt][nt], 0, 0, 0);
        __builtin_amdgcn_s_setprio(0);

        // u-consume -> compiler-counted vmcnt(2): retires last iter's B DMAs,
        // keeps this iter's 2 in flight across the barrier.
        if (kq < 15) write_A(abuf ^ 1, kq + 1);
        asm volatile("s_waitcnt lgkmcnt(0)\n\ts_barrier" ::: "memory");
        const int t3 = bcur; bcur = bnxt; bnxt = bstg; bstg = t3;
    }

    // epilogue: relu(C + qterm), each wave reduces its 64 m-rows x 64 n-cols
    #pragma unroll
    for (int nt = 0; nt < 4; ++nt) {
        const float q = qterm[b * G1_ + nbase + nloc + nt * 16 + l15];
        float s = 0.f;
        #pragma unroll
        for (int mt = 0; mt < 4; ++mt)
            #pragma unroll
            for (int r = 0; r < 4; ++r)
                s += fmaxf(acc[mt][nt][r] + q, 0.f);
        s += __shfl_xor(s, 16, 64);
        s += __shfl_xor(s, 32, 64);
        if (quad == 0) ebuf[wave][nt * 16 + l15] = s;
    }
    __syncthreads();
    if (tid < 256) {
        const float sv = ebuf[tid >> 6][tid & 63] + ebuf[4 + (tid >> 6)][tid & 63];
        atomicAdd(xg + b * G1_ + nbase + tid, sv);
    }
}

// ---------------------------------------------------------------------------
// k_f1 (R8/R10-measured): one wave per output dot, transposed weights.
__global__ void k_f1(const float* __restrict__ xg, const float* __restrict__ f1t,
                     const float* __restrict__ f1b, float* __restrict__ s1g) {
    const int wave = threadIdx.x >> 6, lane = threadIdx.x & 63;
    const int id = blockIdx.x * 4 + wave;         // [0,4096)
    const int b = id >> 9, oo = id & 511;
    const float* xr = xg + b * G1_ + lane * 8;
    const float* wr = f1t + oo * G1_ + lane * 8;
    const float4 a0 = *(const float4*)xr, a1 = *(const float4*)(xr + 4);
    const float4 b0 = *(const float4*)wr, b1 = *(const float4*)(wr + 4);
    float s = a0.x*b0.x + a0.y*b0.y + a0.z*b0.z + a0.w*b0.w
            + a1.x*b1.x + a1.y*b1.y + a1.z*b1.z + a1.w*b1.w;
    #pragma unroll
    for (int off = 32; off >= 1; off >>= 1) s += __shfl_xor(s, off, 64);
    if (lane == 0) s1g[b * F1_ + oo] = fmaxf(s + f1b[oo], 0.f);
}

// ---------------------------------------------------------------------------
// k_f23 R16: f2 + (last-block) f3. 1024 blocks x 512 threads; f2 mapping
// identical to the measured k_f2 (8192 dots, one per wave). Last-ARRIVING
// block (acq_rel ticket == 1023) computes f3 + log_softmax itself.
// Deadlock-free: no block ever waits on another block's progress.
__global__ __launch_bounds__(512)
void k_f23(const float* __restrict__ s1g, const float* __restrict__ f2t,
           const float* __restrict__ f2b, const float* __restrict__ f3t,
           const float* __restrict__ f3b, float* __restrict__ s2g,
           float* __restrict__ out, unsigned* __restrict__ cnt) {
    const int tid = threadIdx.x;
    const int wave = tid >> 6, lane = tid & 63;
    {
        const int id = blockIdx.x * 8 + wave;     // [0,8192)
        const int b = id >> 10, oo = id & 1023;
        const float* xr = s1g + b * F1_ + lane * 8;
        const float* wr = f2t + (size_t)oo * F1_ + lane * 8;
        const float4 a0 = *(const float4*)xr, a1 = *(const float4*)(xr + 4);
        const float4 b0 = *(const float4*)wr, b1 = *(const float4*)(wr + 4);
        float s = a0.x*b0.x + a0.y*b0.y + a0.z*b0.z + a0.w*b0.w
                + a1.x*b1.x + a1.y*b1.y + a1.z*b1.z + a1.w*b1.w;
        #pragma unroll
        for (int off = 32; off >= 1; off >>= 1) s += __shfl_xor(s, off, 64);
        if (lane == 0) s2g[b * F2_ + oo] = fmaxf(s + f2b[oo], 0.f);
    }
    // ---- last-arriving block takes the ticket and runs f3 ----
    __shared__ unsigned lastf;
    __syncthreads();                 // all waves' s2g stores drained (vmcnt)
    __threadfence();                 // release: publish s2g device-wide
    if (tid == 0) {
        const unsigned old = __hip_atomic_fetch_add(
            cnt, 1u, __ATOMIC_ACQ_REL, __HIP_MEMORY_SCOPE_AGENT);
        lastf = (old == 1023u);
    }
    __syncthreads();
    if (!lastf) return;
    __threadfence();                 // acquire: see all blocks' s2g stores

    __shared__ float lg[8][16];
    for (int d = wave; d < 128; d += 8) {     // 128 dots = 8 batches x 16 out
        const int b3 = d >> 4, o = d & 15;
        const float* xr = s2g + b3 * F2_ + lane * 16;
        const float* wr = f3t + (size_t)o * F2_ + lane * 16;
        float s = 0.f;
        #pragma unroll
        for (int j = 0; j < 4; ++j) {
            const float4 xv = *(const float4*)(xr + j * 4);
            const float4 wv = *(const float4*)(wr + j * 4);
            s += xv.x*wv.x + xv.y*wv.y + xv.z*wv.z + xv.w*wv.w;
        }
        #pragma unroll
        for (int off = 32; off >= 1; off >>= 1) s += __shfl_xor(s, off, 64);
        if (lane == 0) lg[b3][o] = s + f3b[o];
    }
    __syncthreads();
    if (tid < 128) {
        const int b3 = tid >> 4, o = tid & 15;
        float m = -1e30f;
        #pragma unroll
        for (int i = 0; i < 16; ++i) m = fmaxf(m, lg[b3][i]);
        float se = 0.f;
        #pragma unroll
        for (int i = 0; i < 16; ++i) se += __expf(lg[b3][i] - m);
        out[b3 * OUT_ + o] = lg[b3][o] - m - logf(se);
    }
}

// ---------------------------------------------------------------------------
extern "C" void kernel_launch(void* const* d_in, const int* in_sizes, int n_in,
                              void* d_out, int out_size, void* d_ws, size_t ws_size,
                              hipStream_t stream) {
    const float* x   = (const float*)d_in[0];
    const float* qst = (const float*)d_in[1];
    const float* g0w = (const float*)d_in[2];
    const float* g0b = (const float*)d_in[3];
    const float* g1w = (const float*)d_in[4];
    const float* g1b = (const float*)d_in[5];
    const float* f1w = (const float*)d_in[6];
    const float* f1b = (const float*)d_in[7];
    const float* f2w = (const float*)d_in[8];
    const float* f2b = (const float*)d_in[9];
    const float* f3w = (const float*)d_in[10];
    const float* f3b = (const float*)d_in[11];

    char* ws = (char*)d_ws;
    float*  u     = (float*)ws;  ws += (size_t)B_ * D_ * G0P * 4;   // 2 MB
    float*  v     = (float*)ws;  ws += (size_t)B_ * D_ * G0P * 4;   // 2 MB
    __bf16* w1t   = (__bf16*)ws; ws += (size_t)G1_ * G0P * 2;       // 512 KB
    float*  qterm = (float*)ws;  ws += (size_t)B_ * G1_ * 4;
    float*  xg    = (float*)ws;  ws += (size_t)B_ * G1_ * 4;
    float*  s1g   = (float*)ws;  ws += (size_t)B_ * F1_ * 4;
    float*  s2g   = (float*)ws;  ws += (size_t)B_ * F2_ * 4;
    float*  f1t   = (float*)ws;  ws += (size_t)F1_ * G1_ * 4;       // 1 MB
    float*  f2t   = (float*)ws;  ws += (size_t)F2_ * F1_ * 4;       // 2 MB
    float*  f3t   = (float*)ws;  ws += (size_t)OUT_ * F2_ * 4;      // 64 KB
    unsigned* cnt = (unsigned*)ws; ws += 256;

    k_prep<<<2092, 256, 0, stream>>>(x, g0w, g0b, qst, g1w, g1b, f1w, f2w, f3w,
                                     u, v, w1t, qterm, xg, f1t, f2t, f3t, cnt);
    k_pair<<<B_ * D_ * 2, 512, 0, stream>>>(u, v, w1t, qterm, xg);
    k_f1  <<<1024, 256, 0, stream>>>(xg, f1t, f1b, s1g);
    k_f23 <<<1024, 512, 0, stream>>>(s1g, f2t, f2b, f3t, f3b, s2g,
                                     (float*)d_out, cnt);
}

// Round 14
// 170.657 us; speedup vs baseline: 1.8678x; 1.8678x over previous
//
#include <hip/hip_runtime.h>
#include <hip/hip_bf16.h>

#define B_  8
#define D_  128
#define K_  7
#define Q_  256
#define G0_ 511
#define G0P 512
#define G1_ 512
#define F1_ 512
#define F2_ 1024
#define OUT_ 16

typedef __bf16 bf16x8 __attribute__((ext_vector_type(8)));
typedef float  f32x4  __attribute__((ext_vector_type(4)));

// async global->LDS: one instruction = 64 lanes x 16B = 1KB.
// LDS dest = wave-uniform base + lane*16B.
#define GL2LDS(g, l) __builtin_amdgcn_global_load_lds(                        \
    (const __attribute__((address_space(1))) void*)(g),                       \
    (__attribute__((address_space(3))) void*)(l), 16, 0, 0)

// ---------------------------------------------------------------------------
// k_prep: fused preprocessing, 2092 blocks x 256 threads (R8/R10-measured).
__global__ void k_prep(const float* __restrict__ x, const float* __restrict__ g0w,
                       const float* __restrict__ g0b, const float* __restrict__ qst,
                       const float* __restrict__ g1w, const float* __restrict__ g1b,
                       const float* __restrict__ f1w, const float* __restrict__ f2w,
                       const float* __restrict__ f3w,
                       float* __restrict__ u, float* __restrict__ v,
                       __bf16* __restrict__ w1t, float* __restrict__ qterm,
                       float* __restrict__ xg, float* __restrict__ f1t,
                       float* __restrict__ f2t, float* __restrict__ f3t) {
    const int blk = blockIdx.x;
    const int t   = threadIdx.x;
    if (blk < 1024) {
        __shared__ float xs[8];
        if (t < K_) xs[t] = x[blk * K_ + t];
        __syncthreads();
        #pragma unroll
        for (int h = 0; h < 2; ++h) {
            const int g = t + h * 256;
            float su = 0.f, sv = 0.f;
            if (g < G0_) {
                #pragma unroll
                for (int k = 0; k < K_; ++k) {
                    su += xs[k] * g0w[k * G0_ + g];
                    sv += xs[k] * g0w[(K_ + k) * G0_ + g];
                }
                su += g0b[g];
            }
            u[blk * G0P + g] = (g < G0_) ? su : 0.f;
            v[blk * G0P + g] = (g < G0_) ? sv : 0.f;
        }
    } else if (blk < 1280) {
        // R3-verified: w1t[kq*16384 + n*32 + slot*8 + j], slot = chunk^((n>>1)&3)
        __shared__ __bf16 tile[32][33];
        const int bb = blk - 1024;
        const int bx = bb & 15, by = bb >> 4;   // by = kq tile (k = by*32+c)
        const int r = t >> 5, c = t & 31;
        #pragma unroll
        for (int i = 0; i < 4; ++i) {
            const int k = by * 32 + r + i * 8;
            const int n = bx * 32 + c;
            tile[r + i * 8][c] = (__bf16)((k < G0_) ? g1w[k * G1_ + n] : 0.f);
        }
        __syncthreads();
        #pragma unroll
        for (int i = 0; i < 4; ++i) {
            const int n = bx * 32 + r + i * 8;
            const int cc = (c >> 3) & 3, j = c & 7;
            const int slot = cc ^ ((n >> 1) & 3);
            w1t[by * 16384 + n * 32 + slot * 8 + j] = tile[c][r + i * 8];
        }
    } else if (blk < 1312) {
        __shared__ float qs[256];
        __shared__ float red[2][128];
        const int qb = blk - 1280;
        const int b = qb >> 2, nb = (qb & 3) << 7;
        qs[t] = qst[b * Q_ + t];
        __syncthreads();
        const int n = nb + (t & 127);
        const int qh = (t >> 7) * 128;
        float s = 0.f;
        #pragma unroll 8
        for (int q = 0; q < 128; ++q)
            s += qs[qh + q] * g1w[(G0_ + qh + q) * G1_ + n];
        red[t >> 7][t & 127] = s;
        __syncthreads();
        if (t < 128)
            qterm[b * G1_ + nb + t] = red[0][t] + red[1][t] + g1b[nb + t];
    } else if (blk < 1320) {
        const int b = blk - 1312;
        xg[b * G1_ + t] = 0.f;
        xg[b * G1_ + 256 + t] = 0.f;
    } else if (blk < 1576) {
        __shared__ float tile[32][33];
        const int j = blk - 1320;
        const int bo = j & 15, bk = j >> 4;
        const int r = t >> 5, c = t & 31;
        #pragma unroll
        for (int i = 0; i < 4; ++i)
            tile[r + i * 8][c] = f1w[(bk * 32 + r + i * 8) * F1_ + bo * 32 + c];
        __syncthreads();
        #pragma unroll
        for (int i = 0; i < 4; ++i)
            f1t[(bo * 32 + r + i * 8) * G1_ + bk * 32 + c] = tile[c][r + i * 8];
    } else if (blk < 2088) {
        __shared__ float tile[32][33];
        const int j = blk - 1576;
        const int bo = j & 31, bk = j >> 5;
        const int r = t >> 5, c = t & 31;
        #pragma unroll
        for (int i = 0; i < 4; ++i)
            tile[r + i * 8][c] = f2w[(bk * 32 + r + i * 8) * F2_ + bo * 32 + c];
        __syncthreads();
        #pragma unroll
        for (int i = 0; i < 4; ++i)
            f2t[(bo * 32 + r + i * 8) * F1_ + bk * 32 + c] = tile[c][r + i * 8];
    } else {
        const int k = (blk - 2088) * 256 + t;
        float4 r0 = *(const float4*)(f3w + k * OUT_);
        float4 r1 = *(const float4*)(f3w + k * OUT_ + 4);
        float4 r2 = *(const float4*)(f3w + k * OUT_ + 8);
        float4 r3 = *(const float4*)(f3w + k * OUT_ + 12);
        const float rr[16] = {r0.x,r0.y,r0.z,r0.w, r1.x,r1.y,r1.z,r1.w,
                              r2.x,r2.y,r2.z,r2.w, r3.x,r3.y,r3.z,r3.w};
        #pragma unroll
        for (int o = 0; o < 16; ++o) f3t[o * F2_ + k] = rr[o];
    }
}

// ---------------------------------------------------------------------------
// k_pair = R10/R15's measured-best core (pair 85.0 us): 512 thr, 64x64/wave,
// acc[4][4], __launch_bounds__(512,4) (4 waves/SIMD; R12 proved 6 spills),
// counted-vmcnt 3-deep Bt, conflict-free XOR-swizzled At, T5 setprio.
__global__ __launch_bounds__(512, 4)
void k_pair(const float* __restrict__ u, const float* __restrict__ v,
            const __bf16* __restrict__ w1t, const float* __restrict__ qterm,
            float* __restrict__ xg) {
    __shared__ float  v_a[512];
    __shared__ __bf16 At[2][4096];     // [buf][mtile(8)][lane(64)*8]  16 KB
    __shared__ __bf16 Bt[3][8192];     // [buf][n_local(256)][32k swz] 48 KB
    __shared__ float  ebuf[8][64];

    const int bid  = blockIdx.x;
    const int b    = bid >> 8;
    const int a    = (bid >> 1) & 127;
    const int nbase = (bid & 1) << 8;
    const int tid  = threadIdx.x;
    const int wave = tid >> 6, lane = tid & 63;
    const int quad = lane >> 4, l15 = lane & 15;
    const int wm   = wave >> 2;            // m-half: rows [wm*64, +64)
    const int wn   = wave & 3;             // n-quarter: cols [wn*64, +64)
    const int nloc = wn * 64;
    const int mtg  = wm * 4;               // wave's mtile base (4 mtiles)
    const int swz  = (l15 >> 1) & 3;

    // B staging: wave issues 2 DMA instrs, instr j covers n_local [wave*32+j*16,+16)
    const int iw0 = wave * 2;
    const __bf16* gsrc = w1t + (size_t)(nbase + iw0 * 16 + (lane >> 2)) * 32
                             + (lane & 3) * 8;

    // A staging geometry: thread -> (m = tid>>2, k-off = (tid&3)*8), XOR-swizzled
    const int sm = tid >> 2;
    const int q8 = tid & 3;
    const float* urow = u + (size_t)(b * D_ + sm) * G0P + q8 * 8;
    const int woff = ((sm >> 4) * 512 + q8 * 128 + (sm & 15) * 8)
                   ^ (((q8 << 1) | ((sm >> 3) & 1)) << 3);
    // swizzled read lane offset: elem lane*8 with byte-bits[7:9] XORed into [4:6]
    const int afoff = (lane ^ (lane >> 3)) * 8;

    f32x4 acc[4][4];
    #pragma unroll
    for (int mt = 0; mt < 4; ++mt)
        #pragma unroll
        for (int nt = 0; nt < 4; ++nt)
            acc[mt][nt] = (f32x4){0.f, 0.f, 0.f, 0.f};

    float4 ua, ub;
    auto load_u = [&](int kq) {
        const float* p = urow + kq * 32;
        ua = *(const float4*)p;
        ub = *(const float4*)(p + 4);
    };
    auto stage_B = [&](int buf, int kq) {
        const __bf16* g = gsrc + (size_t)kq * 16384;
        __bf16* l = &Bt[buf][iw0 * 512];
        GL2LDS(g, l);
        GL2LDS(g + 512, l + 512);
    };
    auto write_A = [&](int buf, int kq) {
        const float* vp = v_a + kq * 32 + q8 * 8;
        const float4 va = *(const float4*)vp;
        const float4 vb = *(const float4*)(vp + 4);
        bf16x8 h;
        h[0] = (__bf16)fmaxf(ua.x + va.x, 0.f);
        h[1] = (__bf16)fmaxf(ua.y + va.y, 0.f);
        h[2] = (__bf16)fmaxf(ua.z + va.z, 0.f);
        h[3] = (__bf16)fmaxf(ua.w + va.w, 0.f);
        h[4] = (__bf16)fmaxf(ub.x + vb.x, 0.f);
        h[5] = (__bf16)fmaxf(ub.y + vb.y, 0.f);
        h[6] = (__bf16)fmaxf(ub.z + vb.z, 0.f);
        h[7] = (__bf16)fmaxf(ub.w + vb.w, 0.f);
        *(bf16x8*)&At[buf][woff] = h;
    };

    // ---- prologue (R4 invariants, counts adjusted to 2 u + 2 DMA) ----
    // vmcnt FIFO: v-row, u(0) x2, || fence ||, DMA buf0 x2, DMA buf1 x2.
    float4 vq;
    if (tid < 128) vq = *(const float4*)(v + (b * D_ + a) * G0P + tid * 4);
    load_u(0);
    asm volatile("" ::: "memory");       // pin: v/u loads issue before DMAs
    stage_B(0, 0);
    stage_B(1, 1);
    if (tid < 128) *(float4*)(v_a + tid * 4) = vq;   // waits v (counted)
    asm volatile("s_waitcnt lgkmcnt(0)\n\ts_barrier" ::: "memory");  // v_a visible
    write_A(0, 0);                        // u-consume: vmcnt(4), DMAs stay out
    // drain own buf0 DMAs (2 oldest), keep buf1's 2 in flight; publish At[0]
    asm volatile("s_waitcnt vmcnt(2) lgkmcnt(0)\n\ts_barrier" ::: "memory");

    int bcur = 0, bnxt = 1, bstg = 2;
    for (int kq = 0; kq < 16; ++kq) {
        const int abuf = kq & 1;
        if (kq < 15) load_u(kq + 1);          // issue u first (older than DMA)
        asm volatile("" ::: "memory");        // pin u before DMA in vmcnt FIFO
        if (kq < 14) stage_B(bstg, kq + 2);   // async DMA, 2 iterations ahead

        bf16x8 af[4];
        const __bf16* atb = &At[abuf][mtg * 512 + afoff];
        #pragma unroll
        for (int mt = 0; mt < 4; ++mt)
            af[mt] = *(const bf16x8*)(atb + mt * 512);
        bf16x8 bfr[4];
        const __bf16* btb = &Bt[bcur][(nloc + l15) * 32 + ((quad ^ swz) << 3)];
        #pragma unroll
        for (int nt = 0; nt < 4; ++nt)
            bfr[nt] = *(const bf16x8*)(btb + nt * 512);
        __builtin_amdgcn_s_setprio(1);
        #pragma unroll
        for (int mt = 0; mt < 4; ++mt)
            #pragma unroll
            for (int nt = 0; nt < 4; ++nt)
                acc[mt][nt] = __builtin_amdgcn_mfma_f32_16x16x32_bf16(
                    af[mt], bfr[nt], acc[mt][nt], 0, 0, 0);
        __builtin_amdgcn_s_setprio(0);

        // u-consume -> compiler-counted vmcnt(2): retires last iter's B DMAs,
        // keeps this iter's 2 in flight across the barrier.
        if (kq < 15) write_A(abuf ^ 1, kq + 1);
        asm volatile("s_waitcnt lgkmcnt(0)\n\ts_barrier" ::: "memory");
        const int t3 = bcur; bcur = bnxt; bnxt = bstg; bstg = t3;
    }

    // epilogue: relu(C + qterm), each wave reduces its 64 m-rows x 64 n-cols
    #pragma unroll
    for (int nt = 0; nt < 4; ++nt) {
        const float q = qterm[b * G1_ + nbase + nloc + nt * 16 + l15];
        float s = 0.f;
        #pragma unroll
        for (int mt = 0; mt < 4; ++mt)
            #pragma unroll
            for (int r = 0; r < 4; ++r)
                s += fmaxf(acc[mt][nt][r] + q, 0.f);
        s += __shfl_xor(s, 16, 64);
        s += __shfl_xor(s, 32, 64);
        if (quad == 0) ebuf[wave][nt * 16 + l15] = s;
    }
    __syncthreads();
    if (tid < 256) {
        const float sv = ebuf[tid >> 6][tid & 63] + ebuf[4 + (tid >> 6)][tid & 63];
        atomicAdd(xg + b * G1_ + nbase + tid, sv);
    }
}

// ---------------------------------------------------------------------------
// f-MLP (R8/R10-measured): one wave per output dot, transposed weights,
// massive TLP (1024-2048 blocks) hides dependent-load latency.
__global__ void k_f1(const float* __restrict__ xg, const float* __restrict__ f1t,
                     const float* __restrict__ f1b, float* __restrict__ s1g) {
    const int wave = threadIdx.x >> 6, lane = threadIdx.x & 63;
    const int id = blockIdx.x * 4 + wave;         // [0,4096)
    const int b = id >> 9, oo = id & 511;
    const float* xr = xg + b * G1_ + lane * 8;
    const float* wr = f1t + oo * G1_ + lane * 8;
    const float4 a0 = *(const float4*)xr, a1 = *(const float4*)(xr + 4);
    const float4 b0 = *(const float4*)wr, b1 = *(const float4*)(wr + 4);
    float s = a0.x*b0.x + a0.y*b0.y + a0.z*b0.z + a0.w*b0.w
            + a1.x*b1.x + a1.y*b1.y + a1.z*b1.z + a1.w*b1.w;
    #pragma unroll
    for (int off = 32; off >= 1; off >>= 1) s += __shfl_xor(s, off, 64);
    if (lane == 0) s1g[b * F1_ + oo] = fmaxf(s + f1b[oo], 0.f);
}

__global__ void k_f2(const float* __restrict__ s1g, const float* __restrict__ f2t,
                     const float* __restrict__ f2b, float* __restrict__ s2g) {
    const int wave = threadIdx.x >> 6, lane = threadIdx.x & 63;
    const int id = blockIdx.x * 4 + wave;         // [0,8192)
    const int b = id >> 10, oo = id & 1023;
    const float* xr = s1g + b * F1_ + lane * 8;
    const float* wr = f2t + oo * F1_ + lane * 8;
    const float4 a0 = *(const float4*)xr, a1 = *(const float4*)(xr + 4);
    const float4 b0 = *(const float4*)wr, b1 = *(const float4*)(wr + 4);
    float s = a0.x*b0.x + a0.y*b0.y + a0.z*b0.z + a0.w*b0.w
            + a1.x*b1.x + a1.y*b1.y + a1.z*b1.z + a1.w*b1.w;
    #pragma unroll
    for (int off = 32; off >= 1; off >>= 1) s += __shfl_xor(s, off, 64);
    if (lane == 0) s2g[b * F2_ + oo] = fmaxf(s + f2b[oo], 0.f);
}

__global__ void k_f3(const float* __restrict__ s2g, const float* __restrict__ f3t,
                     const float* __restrict__ f3b, float* __restrict__ out) {
    const int b = blockIdx.x, t = threadIdx.x;
    const int wave = t >> 6, lane = t & 63;
    __shared__ float lg[16];
    float4 xs[4];
    #pragma unroll
    for (int j = 0; j < 4; ++j)
        xs[j] = *(const float4*)(s2g + b * F2_ + lane * 16 + j * 4);
    #pragma unroll
    for (int oi = 0; oi < 4; ++oi) {
        const int o = wave * 4 + oi;
        const float* wr = f3t + o * F2_ + lane * 16;
        float s = 0.f;
        #pragma unroll
        for (int j = 0; j < 4; ++j) {
            const float4 w = *(const float4*)(wr + j * 4);
            s += xs[j].x*w.x + xs[j].y*w.y + xs[j].z*w.z + xs[j].w*w.w;
        }
        #pragma unroll
        for (int off = 32; off >= 1; off >>= 1) s += __shfl_xor(s, off, 64);
        if (lane == 0) lg[o] = s + f3b[o];
    }
    __syncthreads();
    if (t < 16) {
        float m = -1e30f;
        #pragma unroll
        for (int i = 0; i < 16; ++i) m = fmaxf(m, lg[i]);
        float se = 0.f;
        #pragma unroll
        for (int i = 0; i < 16; ++i) se += __expf(lg[i] - m);
        out[b * OUT_ + t] = lg[t] - m - logf(se);
    }
}

// ---------------------------------------------------------------------------
extern "C" void kernel_launch(void* const* d_in, const int* in_sizes, int n_in,
                              void* d_out, int out_size, void* d_ws, size_t ws_size,
                              hipStream_t stream) {
    const float* x   = (const float*)d_in[0];
    const float* qst = (const float*)d_in[1];
    const float* g0w = (const float*)d_in[2];
    const float* g0b = (const float*)d_in[3];
    const float* g1w = (const float*)d_in[4];
    const float* g1b = (const float*)d_in[5];
    const float* f1w = (const float*)d_in[6];
    const float* f1b = (const float*)d_in[7];
    const float* f2w = (const float*)d_in[8];
    const float* f2b = (const float*)d_in[9];
    const float* f3w = (const float*)d_in[10];
    const float* f3b = (const float*)d_in[11];

    char* ws = (char*)d_ws;
    float*  u     = (float*)ws;  ws += (size_t)B_ * D_ * G0P * 4;   // 2 MB
    float*  v     = (float*)ws;  ws += (size_t)B_ * D_ * G0P * 4;   // 2 MB
    __bf16* w1t   = (__bf16*)ws; ws += (size_t)G1_ * G0P * 2;       // 512 KB
    float*  qterm = (float*)ws;  ws += (size_t)B_ * G1_ * 4;
    float*  xg    = (float*)ws;  ws += (size_t)B_ * G1_ * 4;
    float*  s1g   = (float*)ws;  ws += (size_t)B_ * F1_ * 4;
    float*  s2g   = (float*)ws;  ws += (size_t)B_ * F2_ * 4;
    float*  f1t   = (float*)ws;  ws += (size_t)F1_ * G1_ * 4;       // 1 MB
    float*  f2t   = (float*)ws;  ws += (size_t)F2_ * F1_ * 4;       // 2 MB
    float*  f3t   = (float*)ws;  ws += (size_t)OUT_ * F2_ * 4;      // 64 KB

    k_prep<<<2092, 256, 0, stream>>>(x, g0w, g0b, qst, g1w, g1b, f1w, f2w, f3w,
                                     u, v, w1t, qterm, xg, f1t, f2t, f3t);
    k_pair<<<B_ * D_ * 2, 512, 0, stream>>>(u, v, w1t, qterm, xg);
    k_f1  <<<1024, 256, 0, stream>>>(xg, f1t, f1b, s1g);
    k_f2  <<<2048, 256, 0, stream>>>(s1g, f2t, f2b, s2g);
    k_f3  <<<B_, 256, 0, stream>>>(s2g, f3t, f3b, (float*)d_out);
}